// Round 9
// baseline (54.097 us; speedup 1.0000x reference)
//
#include <hip/hip_runtime.h>

#define F_IN  128
#define HID   16
#define CF_IN 64
#define NTHR  256

typedef __attribute__((ext_vector_type(16))) float f32x16;

// Stream 2 weight rows (32 floats) into SGPRs. The s_waitcnt lives in the SAME
// asm block that defines the outputs, so every consumer FMA has a true data
// dependency on the completed load -- no fence/hoist hazard (rule #18).
// SMEM returns can be out-of-order: only lgkmcnt(0) is safe. No DS ops exist
// in the hot loop, so nothing else pollutes lgkmcnt.
#define WCHUNK(W0, W1V, PTR)                                      \
    asm volatile("s_load_dwordx16 %0, %2, 0\n\t"                  \
                 "s_load_dwordx16 %1, %2, 64\n\t"                 \
                 "s_waitcnt lgkmcnt(0)"                           \
                 : "=s"(W0), "=s"(W1V)                            \
                 : "s"(PTR))

#define FMA16(ACC, XS, W)                                         \
    _Pragma("unroll")                                             \
    for (int _j = 0; _j < 16; ++_j) ACC[_j] = fmaf(XS, W[_j], ACC[_j])

// GCN aggregation is exactly the identity here (row==col after the reference's
// broadcast+reshape), so each conv is x@W + b. edge_index is never read.
//
// Node path: thread-per-node; W1/W2/Wn stream through SGPRs (scalar pipe,
// broadcast-free: v_fma with SGPR src0 costs zero per-lane delivery). R1/R5/R8
// all plateaued at ~38-42us because every lane privately received 8KB of W1
// through the ~128B/cyc/CU return path (~21us) -- SGPR operands remove that
// term entirely. x stays per-lane float4 streaming (L3-resident on replays).

__global__ __launch_bounds__(NTHR) void fused_kernel(
    const float* __restrict__ x, const float* __restrict__ xc,
    const float* __restrict__ W1, const float* __restrict__ b1,
    const float* __restrict__ W2, const float* __restrict__ b2,
    const float* __restrict__ Wn, const float* __restrict__ bn,
    const float* __restrict__ Wc1, const float* __restrict__ bc1,
    const float* __restrict__ Wc2, const float* __restrict__ bc2,
    float* __restrict__ pN, float* __restrict__ pC,
    int N, int B, int C, int totalN, int nodeBlocks, int colBlocks)
{
    __shared__ float sred[4 * 8];   // [wave][batch<=8] partials only
    const int t = threadIdx.x;
    const int bx = blockIdx.x;
    const int wave = t >> 6;

    if (bx < nodeBlocks) {
        // ---------------- node path ----------------
        const int n = bx * NTHR + t;
        const bool valid = (n < totalN);
        const int nc = valid ? n : totalN - 1;
        const float4* __restrict__ row = (const float4*)(x + (long)nc * F_IN);

        float acc[HID];
        {
            f32x16 bv;
            asm volatile("s_load_dwordx16 %0, %1, 0\n\ts_waitcnt lgkmcnt(0)"
                         : "=s"(bv) : "s"(b1));
#pragma unroll
            for (int j = 0; j < HID; ++j) acc[j] = bv[j];
        }

        // layer 1: K=128, weights via SGPR chunks of 2 k-rows
        const float* wp = W1;
#pragma unroll 4
        for (int k4 = 0; k4 < F_IN / 4; ++k4) {
            const float4 xv = row[k4];
            f32x16 wa, wb;
            WCHUNK(wa, wb, wp);            // k-rows 4k4+0, 4k4+1
            FMA16(acc, xv.x, wa);
            FMA16(acc, xv.y, wb);
            f32x16 wc, wd;
            WCHUNK(wc, wd, wp + 32);       // k-rows 4k4+2, 4k4+3
            FMA16(acc, xv.z, wc);
            FMA16(acc, xv.w, wd);
            wp += 64;
        }

        // layer 2 (16x16): same SGPR streaming
        float h1[HID];
#pragma unroll
        for (int j = 0; j < HID; ++j) h1[j] = fmaxf(acc[j], 0.f);
        float h2[HID];
        {
            f32x16 bv;
            asm volatile("s_load_dwordx16 %0, %1, 0\n\ts_waitcnt lgkmcnt(0)"
                         : "=s"(bv) : "s"(b2));
#pragma unroll
            for (int j = 0; j < HID; ++j) h2[j] = bv[j];
        }
        const float* wp2 = W2;
#pragma unroll
        for (int kk = 0; kk < 8; ++kk) {
            f32x16 wa, wb;
            WCHUNK(wa, wb, wp2);           // k-rows 2kk, 2kk+1
            FMA16(h2, h1[2 * kk + 0], wa);
            FMA16(h2, h1[2 * kk + 1], wb);
            wp2 += 32;
        }

        // layer 3 (16 -> 1)
        float o;
        {
            f32x16 wn;
            asm volatile("s_load_dwordx16 %0, %1, 0\n\ts_waitcnt lgkmcnt(0)"
                         : "=s"(wn) : "s"(Wn));
            o = bn[0];
#pragma unroll
            for (int j = 0; j < HID; ++j)
                o = fmaf(fmaxf(h2[j], 0.f), wn[j], o);
        }

        const int myb = nc / N;
        const float val = valid ? o : 0.f;

        // per-batch masked block reduction (deterministic)
        for (int b = 0; b < B; ++b) {
            float s = (myb == b) ? val : 0.f;
#pragma unroll
            for (int off = 32; off; off >>= 1) s += __shfl_down(s, off, 64);
            if ((t & 63) == 0) sred[wave * B + b] = s;
        }
        __syncthreads();
        if (t == 0) {
            for (int b = 0; b < B; ++b)
                pN[(long)b * nodeBlocks + bx] =
                    (sred[0 * B + b] + sred[1 * B + b]) +
                    (sred[2 * B + b] + sred[3 * B + b]);
        }
    } else {
        // ---------------- col path (tiny) ----------------
        const int cb = bx - nodeBlocks;
        const int totC = B * C;
        const int c = cb * NTHR + t;
        const bool valid = (c < totC);
        const int cc = valid ? c : totC - 1;
        const float4* __restrict__ row = (const float4*)(xc + (long)cc * CF_IN);

        float acc[HID];
        {
            f32x16 bv;
            asm volatile("s_load_dwordx16 %0, %1, 0\n\ts_waitcnt lgkmcnt(0)"
                         : "=s"(bv) : "s"(bc1));
#pragma unroll
            for (int j = 0; j < HID; ++j) acc[j] = bv[j];
        }
        const float* wp = Wc1;
#pragma unroll 4
        for (int k4 = 0; k4 < CF_IN / 4; ++k4) {
            const float4 xv = row[k4];
            f32x16 wa, wb;
            WCHUNK(wa, wb, wp);
            FMA16(acc, xv.x, wa);
            FMA16(acc, xv.y, wb);
            f32x16 wc, wd;
            WCHUNK(wc, wd, wp + 32);
            FMA16(acc, xv.z, wc);
            FMA16(acc, xv.w, wd);
            wp += 64;
        }
        float o;
        {
            f32x16 wn;
            asm volatile("s_load_dwordx16 %0, %1, 0\n\ts_waitcnt lgkmcnt(0)"
                         : "=s"(wn) : "s"(Wc2));
            o = bc2[0];
#pragma unroll
            for (int j = 0; j < HID; ++j)
                o = fmaf(fmaxf(acc[j], 0.f), wn[j], o);
        }

        const int myb = cc / C;
        const float val = valid ? o : 0.f;
        for (int b = 0; b < B; ++b) {
            float s = (myb == b) ? val : 0.f;
#pragma unroll
            for (int off = 32; off; off >>= 1) s += __shfl_down(s, off, 64);
            if ((t & 63) == 0) sred[wave * B + b] = s;
        }
        __syncthreads();
        if (t == 0) {
            for (int b = 0; b < B; ++b)
                pC[(long)b * colBlocks + cb] =
                    (sred[0 * B + b] + sred[1 * B + b]) +
                    (sred[2 * B + b] + sred[3 * B + b]);
        }
    }
}

__global__ __launch_bounds__(256) void finish_kernel(
    const float* __restrict__ pN, const float* __restrict__ pC,
    const float* __restrict__ Wf, const float* __restrict__ bf,
    const float* __restrict__ Wo, const float* __restrict__ bo,
    float* __restrict__ out, int nWN, int nWC, int N, int C, int B)
{
    const int t = threadIdx.x;
    const int wave = t >> 6, lane = t & 63;
    __shared__ float s[16];

    for (int p = wave; p < 2 * B; p += 4) {
        const int b = p >> 1, kind = p & 1;
        float v = 0.f;
        if (kind == 0) {
            for (int i = lane; i < nWN; i += 64) v += pN[(long)b * nWN + i];
        } else {
            for (int i = lane; i < nWC; i += 64) v += pC[(long)b * nWC + i];
        }
#pragma unroll
        for (int off = 32; off; off >>= 1) v += __shfl_down(v, off, 64);
        if (lane == 0) s[p] = v;
    }
    __syncthreads();

    if (t == 0) {
        for (int b = 0; b < B; ++b) {
            const float navg = s[2 * b + 0] / (float)N;
            const float cavg = s[2 * b + 1] / (float)C;
            float o = bo[0];
#pragma unroll
            for (int j = 0; j < HID; ++j) {
                const float h = fmaf(navg, Wf[j], fmaf(cavg, Wf[HID + j], bf[j]));
                o = fmaf(fmaxf(h, 0.f), Wo[j], o);
            }
            out[b] = o;
        }
    }
}

extern "C" void kernel_launch(void* const* d_in, const int* in_sizes, int n_in,
                              void* d_out, int out_size, void* d_ws, size_t ws_size,
                              hipStream_t stream) {
    const float* x   = (const float*)d_in[0];
    const float* xc  = (const float*)d_in[1];
    // d_in[2] = edge_index: unused (row==col degeneracy -> GCN aggregation is identity)
    const float* W1  = (const float*)d_in[3];
    const float* b1  = (const float*)d_in[4];
    const float* W2  = (const float*)d_in[5];
    const float* b2  = (const float*)d_in[6];
    const float* Wn  = (const float*)d_in[7];
    const float* bn  = (const float*)d_in[8];
    const float* Wc1 = (const float*)d_in[9];
    const float* bc1 = (const float*)d_in[10];
    const float* Wc2 = (const float*)d_in[11];
    const float* bc2 = (const float*)d_in[12];
    const float* Wf  = (const float*)d_in[13];
    const float* bf  = (const float*)d_in[14];
    const float* Wo  = (const float*)d_in[15];
    const float* bo  = (const float*)d_in[16];

    const int C = 1000;
    const int B = in_sizes[1] / (C * CF_IN);     // col_features [B, 1000, 64]
    const int N = in_sizes[0] / (B * F_IN);      // node_features [B, N, 128]
    const int totalN = B * N;                    // 200000

    const int nodeBlocks = (totalN + NTHR - 1) / NTHR;   // 782
    const int colBlocks  = (B * C + NTHR - 1) / NTHR;    // 8

    float* pN = (float*)d_ws;                    // [B][nodeBlocks], always overwritten
    float* pC = pN + (long)B * nodeBlocks;       // [B][colBlocks]

    fused_kernel<<<nodeBlocks + colBlocks, NTHR, 0, stream>>>(
        x, xc, W1, b1, W2, b2, Wn, bn, Wc1, bc1, Wc2, bc2,
        pN, pC, N, B, C, totalN, nodeBlocks, colBlocks);
    finish_kernel<<<1, 256, 0, stream>>>(pN, pC, Wf, bf, Wo, bo, (float*)d_out,
                                         nodeBlocks, colBlocks, N, C, B);
}